// Round 16
// baseline (690.567 us; speedup 1.0000x reference)
//
#include <hip/hip_runtime.h>
#include <hip/hip_bf16.h>

#define NPTS 100000
#define NPTS_PAD 100096
#define DHID 512
#define EPSV 1e-5f

typedef __attribute__((ext_vector_type(4))) float f32x4;

// ---- workspace layout (bytes) ----
// X/H ROW-MAJOR fp8 e4m3: [NPTS_PAD][KD] (KD=128 input, 512 hidden). Within each 64-byte
// group g of a row, position p holds logical col g*64 + (p&3)*16 + (p>>2)  (R15 permutation,
// kept so epilogue stores are packed dwords). Row-major => each block's h-write footprint is
// ONE contiguous 32KB region (vs 8 chunks scattered 6.4MB apart) -- tests the R14/R15
// write-amplification theory.
// W register-path fp8: Wpack[wid(8)][frag(NK*8)][lane(64)] u64, frag = ks*8 + fn*2 + s;
//   byte q of (ks,fn,s),lane(lg,ln15) = (A-B)[wid*64+fn*16+ln15][ks*64 + (q&3)*16 + s*8 + lg*2 + (q>>2)]
#define OFF_INBF   0UL            // 100096*128 = 12,812,288
#define OFF_W0     12812288UL     // 8*16*64*8  = 65,536
#define OFF_W1     12877824UL     // 8*64*64*8  = 262,144
#define OFF_W2     13139968UL     // 262,144
#define OFF_C0     13402112UL     // 512*4 (pad to 2048)
#define OFF_C1     13404160UL
#define OFF_C2     13406208UL
#define OFF_PARTS  13408256UL     // 1563*512*4 = 3,201,024
#define OFF_PARTS2 16609280UL     // 64*512*4 = 131,072
#define OFF_H1     16756736UL     // 100096*512 = 51,249,152
#define OFF_H2     68005888UL     // 51,249,152  (end 119,255,040)

typedef const __attribute__((address_space(1))) unsigned int* gp_t;
typedef __attribute__((address_space(3))) unsigned int* lp_t;

__device__ __forceinline__ void async_copy16(const void* g, void* l) {
    __builtin_amdgcn_global_load_lds((gp_t)g, (lp_t)l, 16, 0, 0);
}

// pack 4 floats -> 4 fp8 e4m3 bytes (RNE, v_cvt_pk_fp8_f32); a->byte0 .. d->byte3
__device__ __forceinline__ unsigned pack4_fp8(float a, float b, float c, float d) {
    unsigned v = (unsigned)__builtin_amdgcn_cvt_pk_fp8_f32(a, b, 0, false);
    v = (unsigned)__builtin_amdgcn_cvt_pk_fp8_f32(c, d, (int)v, true);
    return v;
}

// ---------- prep: fp32 [NPTS][128] -> fp8 row-major [NPTS_PAD][128] (PERMUTED groups) ------
// group kt of row r: dword m = cols {kt*64 + m, +16+m, +32+m, +48+m}
__global__ __launch_bounds__(256) void cvt_pack_kernel(const float* __restrict__ in,
                                                       unsigned char* __restrict__ out) {
    long total = (long)NPTS * 2;
    long stride = (long)gridDim.x * blockDim.x;
    for (long idx = (long)blockIdx.x * blockDim.x + threadIdx.x; idx < total; idx += stride) {
        int kt = (int)(idx / NPTS);
        long r = idx - (long)kt * NPTS;
        const float* src = in + r * 128 + kt * 64;
        unsigned dw[16];
#pragma unroll
        for (int m = 0; m < 16; ++m)
            dw[m] = pack4_fp8(src[m], src[16 + m], src[32 + m], src[48 + m]);
        uint4* dst = (uint4*)(out + r * 128 + kt * 64);
#pragma unroll
        for (int j = 0; j < 4; ++j)
            dst[j] = make_uint4(dw[4 * j], dw[4 * j + 1], dw[4 * j + 2], dw[4 * j + 3]);
    }
}

// ---------- prep: Wpack = fp8(A - B), register-path layout with PERMUTED k-order ----------
// u = (wid*F + f)*64 + lane, f = ks*8 + fn*2 + s, F = NK*8, lane = lg*16 + ln15
// byte q of the u64: k_local = (q&3)*16 + c0 + (q>>2), c0 = s*8 + lg*2  (matches A positions)
__global__ __launch_bounds__(256) void wpack_all_kernel(const float* __restrict__ A0,
                                                        const float* __restrict__ B0,
                                                        const float* __restrict__ A1,
                                                        const float* __restrict__ B1,
                                                        const float* __restrict__ A2,
                                                        const float* __restrict__ B2,
                                                        unsigned long long* __restrict__ W0,
                                                        unsigned long long* __restrict__ W1,
                                                        unsigned long long* __restrict__ W2) {
    int idx = blockIdx.x * 256 + threadIdx.x;
    const float *A, *B; unsigned long long* W; int KD, u;
    if (idx < 8192)       { A = A0; B = B0; W = W0; KD = 128; u = idx; }
    else if (idx < 40960) { A = A1; B = B1; W = W1; KD = 512; u = idx - 8192; }
    else                  { A = A2; B = B2; W = W2; KD = 512; u = idx - 40960; if (u >= 32768) return; }
    int F = (KD / 64) * 8;
    int lane = u & 63;
    int f = (u >> 6) % F;
    int wid = u / (64 * F);
    int ks = f >> 3, fn = (f >> 1) & 3, s = f & 1;
    int ln15 = lane & 15, lg = lane >> 4;
    int row = wid * 64 + fn * 16 + ln15;
    int c0 = s * 8 + lg * 2;
    const float* sa = A + (long)row * KD + ks * 64;
    const float* sb = B + (long)row * KD + ks * 64;
    unsigned lo = pack4_fp8(sa[c0] - sb[c0], sa[16 + c0] - sb[16 + c0],
                            sa[32 + c0] - sb[32 + c0], sa[48 + c0] - sb[48 + c0]);
    unsigned hi = pack4_fp8(sa[c0 + 1] - sb[c0 + 1], sa[17 + c0] - sb[17 + c0],
                            sa[33 + c0] - sb[33 + c0], sa[49 + c0] - sb[49 + c0]);
    W[u] = ((unsigned long long)hi << 32) | lo;
}

// ---------- colsum of in_set (fp32, deterministic 2-stage) ----------
__global__ __launch_bounds__(256) void colsum_in_kernel(const float* __restrict__ in,
                                                        float* __restrict__ parts) {
    __shared__ float sh[256];
    int t = threadIdx.x, blk = blockIdx.x;
    int c = t & 127, half = t >> 7;
    long rbeg = (long)blk * 196 + half;
    long rend = (long)(blk + 1) * 196; if (rend > NPTS) rend = NPTS;
    float s = 0.f;
    for (long r = rbeg; r < rend; r += 2) s += in[r * 128 + c];
    sh[t] = s;
    __syncthreads();
    if (t < 128) parts[blk * 128 + t] = sh[t] + sh[t + 128];
}

// ---------- generic partial reduce: parts[nparts][width] -> out[grid][width] ----------
__global__ void part_reduceW_kernel(const float* __restrict__ parts, int nparts, int width,
                                    int op, float* __restrict__ out) {
    int g = blockIdx.x, t = threadIdx.x;
    int chunk = (nparts + gridDim.x - 1) / gridDim.x;
    int b0 = g * chunk, b1 = b0 + chunk; if (b1 > nparts) b1 = nparts;
    float s = 0.f;  // identity 0 valid for max too: values are post-relu >= 0
    for (int b = b0; b < b1; ++b) {
        float v = parts[(long)b * width + t];
        s = (op == 0) ? (s + v) : fmaxf(s, v);
    }
    out[(long)g * width + t] = s;
}

// ---------- fold nfold partial rows + GEMV: out[j] = (fold_g p2[g][:]) . Bm[j][:] + bias ----
__global__ __launch_bounds__(64) void gemv_fold_kernel(const float* __restrict__ p2, int nfold,
                                                       int dsum, const float* __restrict__ Bm,
                                                       const float* __restrict__ bias, int op,
                                                       float* __restrict__ out) {
    int j = blockIdx.x, t = threadIdx.x;
    float acc = 0.f;
    for (int d = t; d < dsum; d += 64) {
        float s = 0.f;
        for (int g = 0; g < nfold; ++g) {
            float v = p2[(long)g * dsum + d];
            s = (op == 0) ? (s + v) : fmaxf(s, v);
        }
        acc += s * Bm[(long)j * dsum + d];
    }
#pragma unroll
    for (int m = 32; m >= 1; m >>= 1) acc += __shfl_down(acc, m);
    if (t == 0) out[j] = acc + (bias ? bias[j] : 0.0f);
}

// ---------- fused layer (fp8, zero-sync K-loop + W reg-pipeline, 8 waves x 64 cols) --------
// BM=64, BN=512, 512 threads = 8 waves, wave w owns cols [w*64, w*64+64). acc[4][4].
//  - X staged into LDS ONCE (NK*4KB), one __syncthreads total; row-major source.
//  - W: explicit 1-kstep register double-buffer wbuf[2][8] (statically indexed under full
//    unroll) -- next kstep's 8 L2 loads issue BEFORE the current MFMA cluster (G7/ILP).
//  - K-loop: NO barriers/waits/pins.
//  - Store: row-major + permuted groups -> one packed dword store per (fm,j); block's h
//    footprint = one contiguous 32KB region (write-amplification test).
template<int KD, bool STORE, int REDOP>  // REDOP 0=sum, 1=max
__global__ __launch_bounds__(512, 4)
void layer_kernel(const unsigned char* __restrict__ Xp, const unsigned long long* __restrict__ Wp,
                  const float* __restrict__ cvec, const float* __restrict__ gvec,
                  const float* __restrict__ bvec, unsigned char* __restrict__ Hout,
                  float* __restrict__ red_out) {
    static_assert(KD % 64 == 0, "");
    constexpr int NK = KD / 64;
    __shared__ __align__(128) char smem[NK * 4096];   // X [NK][64][64] fp8; epilogue reuse

    const int t = threadIdx.x;
    const int lane = t & 63;
    const int wid = t >> 6;          // 0..7 : this wave's 64-col slice
    const int ln15 = lane & 15;
    const int lg = lane >> 4;        // 0..3
    const long row0 = (long)blockIdx.x * 64;

    f32x4 acc[4][4];
#pragma unroll
    for (int i = 0; i < 4; ++i)
#pragma unroll
        for (int j = 0; j < 4; ++j) acc[i][j] = (f32x4){0.f, 0.f, 0.f, 0.f};

    // ---- X prologue: stage the whole row-tile (row-major source, same LDS image as R15) ----
    if (t < 256) {
        const int sr = t >> 2;       // 0..63
        const int ss = t & 3;
        const char* Xsrc = (const char*)Xp + (row0 + sr) * KD + ((ss ^ ((sr >> 1) & 3)) * 16);
#pragma unroll
        for (int kt = 0; kt < NK; ++kt)
            async_copy16(Xsrc + kt * 64, smem + kt * 4096 + t * 16);
    }
    __syncthreads();   // compiler emits vmcnt(0)+barrier: all X resident from here on

    // LDS read: row r, k-subtile sub, k-group lg -> swizzled slot (same involution as staging)
#define RD8X(BASE, r, sub) (*(const long*)((BASE) + (r) * 64 + \
        (((((sub) * 2 + (lg >> 1)) ^ (((r) >> 1) & 3)) * 16) + (lg & 1) * 8)))

    // ---- zero-sync K-loop with explicit W double-buffer ----
    const unsigned long long* Wq = Wp + (long)wid * (NK * 8) * 64 + lane;
    long wbuf[2][8];
#pragma unroll
    for (int f = 0; f < 8; ++f) wbuf[0][f] = (long)Wq[f * 64];

#pragma unroll
    for (int ks = 0; ks < NK; ++ks) {
        // prefetch next kstep's W fragments before this kstep's MFMAs (ks literal => static idx)
        if (ks + 1 < NK) {
#pragma unroll
            for (int f = 0; f < 8; ++f)
                wbuf[(ks + 1) & 1][f] = (long)Wq[((ks + 1) * 8 + f) * 64];
        }
        const char* Xs = smem + ks * 4096;
        long a0[4], a1[4];
#pragma unroll
        for (int fm = 0; fm < 4; ++fm) {
            int r = fm * 16 + ln15;
            a0[fm] = RD8X(Xs, r, 0);
            a1[fm] = RD8X(Xs, r, 1);
        }
#pragma unroll
        for (int fn = 0; fn < 4; ++fn) {
#pragma unroll
            for (int fm = 0; fm < 4; ++fm)
                acc[fm][fn] = __builtin_amdgcn_mfma_f32_16x16x32_fp8_fp8(
                    a0[fm], wbuf[ks & 1][fn * 2 + 0], acc[fm][fn], 0, 0, 0);
#pragma unroll
            for (int fm = 0; fm < 4; ++fm)
                acc[fm][fn] = __builtin_amdgcn_mfma_f32_16x16x32_fp8_fp8(
                    a1[fm], wbuf[ks & 1][fn * 2 + 1], acc[fm][fn], 0, 0, 0);
        }
    }
#undef RD8X
    __syncthreads();   // before epilogue reuses LDS

    // ---------------- epilogue (reuses LDS; needs 4608B <= NK*4096 since NK>=2) ----------------
    float* lnred_s = (float*)smem;            // [64][8] = 2048B
    float* lnred_q = (float*)(smem + 2048);   // [64][8] = 2048B
    float* lnmv    = (float*)(smem + 4096);   // [64][2] = 512B

    const int cbase = wid * 64 + ln15;
    float cv[4], gv[4], bv[4];
#pragma unroll
    for (int fn = 0; fn < 4; ++fn) {
        int col = cbase + fn * 16;
        cv[fn] = cvec[col]; gv[fn] = gvec[col]; bv[fn] = bvec[col];
    }

    // add the broadcast c-vector (fp32-exact common term)
#pragma unroll
    for (int fm = 0; fm < 4; ++fm)
#pragma unroll
        for (int fn = 0; fn < 4; ++fn) acc[fm][fn] += cv[fn];

    // per-row sum / sumsq over this wave's 64 cols (shfl tree within 16-lane group)
    float rs[16], rq[16];
#pragma unroll
    for (int fm = 0; fm < 4; ++fm)
#pragma unroll
        for (int j = 0; j < 4; ++j) {
            float s = 0.f, q = 0.f;
#pragma unroll
            for (int fn = 0; fn < 4; ++fn) {
                float x = acc[fm][fn][j];
                s += x; q += x * x;
            }
            rs[fm * 4 + j] = s; rq[fm * 4 + j] = q;
        }
#pragma unroll
    for (int m = 1; m < 16; m <<= 1)
#pragma unroll
        for (int i = 0; i < 16; ++i) {
            rs[i] += __shfl_xor(rs[i], m);
            rq[i] += __shfl_xor(rq[i], m);
        }
    if (ln15 == 0) {
#pragma unroll
        for (int fm = 0; fm < 4; ++fm)
#pragma unroll
            for (int j = 0; j < 4; ++j) {
                int row = fm * 16 + lg * 4 + j;
                lnred_s[row * 8 + wid] = rs[fm * 4 + j];
                lnred_q[row * 8 + wid] = rq[fm * 4 + j];
            }
    }
    __syncthreads();
    if (t < 64) {
        float s = 0.f, q = 0.f;
#pragma unroll
        for (int w = 0; w < 8; ++w) { s += lnred_s[t * 8 + w]; q += lnred_q[t * 8 + w]; }
        float mu = s * (1.0f / 512.0f);
        float var = q * (1.0f / 512.0f) - mu * mu;
        lnmv[t * 2] = mu;
        lnmv[t * 2 + 1] = rsqrtf(var + EPSV);
    }
    __syncthreads();

    // normalize + relu + coalesced permuted row-major store ; invalid rows forced to 0
#pragma unroll
    for (int fm = 0; fm < 4; ++fm)
#pragma unroll
        for (int j = 0; j < 4; ++j) {
            int rloc = fm * 16 + lg * 4 + j;
            long rglob = row0 + rloc;
            bool ok = rglob < NPTS;
            float mu = lnmv[rloc * 2], rstd = lnmv[rloc * 2 + 1];
#pragma unroll
            for (int fn = 0; fn < 4; ++fn) {
                float y = fmaxf((acc[fm][fn][j] - mu) * rstd * gv[fn] + bv[fn], 0.0f);
                acc[fm][fn][j] = ok ? y : 0.0f;
            }
            if (STORE) {
                // row rglob, group wid, positions ln15*4..+3 = fn 0..3 values (zeros for pad
                // rows). Block footprint = rows row0..row0+63 x 512B = one contiguous 32KB.
                unsigned u = pack4_fp8(acc[fm][0][j], acc[fm][1][j], acc[fm][2][j], acc[fm][3][j]);
                *(unsigned*)(Hout + rglob * DHID + wid * 64 + ln15 * 4) = u;
            }
        }

    // column partials over the block's 64 rows (sum or max); cols disjoint across waves
    float cp[4];
#pragma unroll
    for (int fn = 0; fn < 4; ++fn) {
        float p = 0.f;
#pragma unroll
        for (int fm = 0; fm < 4; ++fm)
#pragma unroll
            for (int j = 0; j < 4; ++j) {
                float v = acc[fm][fn][j];
                p = (REDOP == 0) ? (p + v) : fmaxf(p, v);
            }
        cp[fn] = p;
    }
#pragma unroll
    for (int m = 16; m < 64; m <<= 1)
#pragma unroll
        for (int fn = 0; fn < 4; ++fn) {
            float o = __shfl_xor(cp[fn], m);
            cp[fn] = (REDOP == 0) ? (cp[fn] + o) : fmaxf(cp[fn], o);
        }
    if (lane < 16) {
#pragma unroll
        for (int fn = 0; fn < 4; ++fn)
            red_out[(long)blockIdx.x * 512 + wid * 64 + fn * 16 + lane] = cp[fn];
    }
}

extern "C" void kernel_launch(void* const* d_in, const int* in_sizes, int n_in,
                              void* d_out, int out_size, void* d_ws, size_t ws_size,
                              hipStream_t stream) {
    const float* in_set = (const float*)d_in[0];
    const float* A0 = (const float*)d_in[1];
    const float* B0 = (const float*)d_in[2];
    const float* A1 = (const float*)d_in[3];
    const float* B1 = (const float*)d_in[4];
    const float* A2 = (const float*)d_in[5];
    const float* B2 = (const float*)d_in[6];
    const float* ga = (const float*)d_in[7];
    const float* be = (const float*)d_in[8];
    const float* ow = (const float*)d_in[9];
    const float* ob = (const float*)d_in[10];
    float* outp = (float*)d_out;
    char* ws = (char*)d_ws;

    unsigned char* in_f8 = (unsigned char*)(ws + OFF_INBF);
    unsigned long long* W0p = (unsigned long long*)(ws + OFF_W0);
    unsigned long long* W1p = (unsigned long long*)(ws + OFF_W1);
    unsigned long long* W2p = (unsigned long long*)(ws + OFF_W2);
    float* c0 = (float*)(ws + OFF_C0);
    float* c1 = (float*)(ws + OFF_C1);
    float* c2 = (float*)(ws + OFF_C2);
    float* parts = (float*)(ws + OFF_PARTS);
    float* parts2 = (float*)(ws + OFF_PARTS2);
    unsigned char* h1 = (unsigned char*)(ws + OFF_H1);
    unsigned char* h2 = (unsigned char*)(ws + OFF_H2);

    const int nblk = (NPTS + 63) / 64;  // 1563

    cvt_pack_kernel<<<1024, 256, 0, stream>>>(in_set, in_f8);
    wpack_all_kernel<<<288, 256, 0, stream>>>(A0, B0, A1, B1, A2, B2, W0p, W1p, W2p);

    // c0 = colsum(in_set) @ B0^T  (all fp32 — the numerically critical path)
    colsum_in_kernel<<<512, 256, 0, stream>>>(in_set, parts);                       // [512][128]
    part_reduceW_kernel<<<64, 128, 0, stream>>>(parts, 512, 128, 0, parts2);        // [64][128]
    gemv_fold_kernel<<<512, 64, 0, stream>>>(parts2, 64, 128, B0, nullptr, 0, c0);

    layer_kernel<128, true, 0><<<nblk, 512, 0, stream>>>(in_f8, W0p, c0, ga, be, h1, parts);
    part_reduceW_kernel<<<64, 512, 0, stream>>>(parts, nblk, 512, 0, parts2);
    gemv_fold_kernel<<<512, 64, 0, stream>>>(parts2, 64, 512, B1, nullptr, 0, c1);

    layer_kernel<512, true, 0><<<nblk, 512, 0, stream>>>(h1, W1p, c1, ga, be, h2, parts);
    part_reduceW_kernel<<<64, 512, 0, stream>>>(parts, nblk, 512, 0, parts2);
    gemv_fold_kernel<<<512, 64, 0, stream>>>(parts2, 64, 512, B2, nullptr, 0, c2);

    // layer 2: no h3 store; fused column-max partials; final = (max-fold) @ ow^T + ob
    layer_kernel<512, false, 1><<<nblk, 512, 0, stream>>>(h2, W2p, c2, ga, be, nullptr, parts);
    part_reduceW_kernel<<<64, 512, 0, stream>>>(parts, nblk, 512, 1, parts2);
    gemv_fold_kernel<<<256, 64, 0, stream>>>(parts2, 64, 512, ow, ob, 1, outp);
}

// Round 17
// 300.390 us; speedup vs baseline: 2.2989x; 2.2989x over previous
//
#include <hip/hip_runtime.h>
#include <hip/hip_bf16.h>

#define NPTS 100000
#define NPTS_PAD 100096
#define DHID 512
#define EPSV 1e-5f

typedef __attribute__((ext_vector_type(4))) float f32x4;

// ---- workspace layout (bytes) ----
// X/H ROW-MAJOR fp8 e4m3: [NPTS_PAD][KD] (KD=128 input, 512 hidden). Within each 64-byte
// group g of a row, position p holds logical col g*64 + (p&3)*16 + (p>>2)  (permutation kept
// so epilogue stores are packed dwords; each block's h-write = one contiguous 32KB region).
// W register-path fp8: Wpack[wid(8)][frag(NK*8)][lane(64)] u64, frag = ks*8 + fn*2 + s;
//   byte q of (ks,fn,s),lane(lg,ln15) = (A-B)[wid*64+fn*16+ln15][ks*64 + (q&3)*16 + s*8 + lg*2 + (q>>2)]
#define OFF_INBF   0UL            // 100096*128 = 12,812,288
#define OFF_W0     12812288UL     // 8*16*64*8  = 65,536
#define OFF_W1     12877824UL     // 8*64*64*8  = 262,144
#define OFF_W2     13139968UL     // 262,144
#define OFF_C0     13402112UL     // 512*4 (pad to 2048)
#define OFF_C1     13404160UL
#define OFF_C2     13406208UL
#define OFF_PARTS  13408256UL     // 1563*512*4 = 3,201,024
#define OFF_PARTS2 16609280UL     // 64*512*4 = 131,072
#define OFF_PARTS3 16740352UL     // 8*512*4 = 16,384
#define OFF_H1     16756736UL     // 100096*512 = 51,249,152
#define OFF_H2     68005888UL     // 51,249,152  (end 119,255,040)

typedef const __attribute__((address_space(1))) unsigned int* gp_t;
typedef __attribute__((address_space(3))) unsigned int* lp_t;

__device__ __forceinline__ void async_copy16(const void* g, void* l) {
    __builtin_amdgcn_global_load_lds((gp_t)g, (lp_t)l, 16, 0, 0);
}

// pack 4 floats -> 4 fp8 e4m3 bytes (RNE, v_cvt_pk_fp8_f32); a->byte0 .. d->byte3
__device__ __forceinline__ unsigned pack4_fp8(float a, float b, float c, float d) {
    unsigned v = (unsigned)__builtin_amdgcn_cvt_pk_fp8_f32(a, b, 0, false);
    v = (unsigned)__builtin_amdgcn_cvt_pk_fp8_f32(c, d, (int)v, true);
    return v;
}

// ---------- prep: fp32 [NPTS][128] -> fp8 row-major [NPTS_PAD][128] (PERMUTED groups) ------
__global__ __launch_bounds__(256) void cvt_pack_kernel(const float* __restrict__ in,
                                                       unsigned char* __restrict__ out) {
    long total = (long)NPTS * 2;
    long stride = (long)gridDim.x * blockDim.x;
    for (long idx = (long)blockIdx.x * blockDim.x + threadIdx.x; idx < total; idx += stride) {
        int kt = (int)(idx / NPTS);
        long r = idx - (long)kt * NPTS;
        const float* src = in + r * 128 + kt * 64;
        unsigned dw[16];
#pragma unroll
        for (int m = 0; m < 16; ++m)
            dw[m] = pack4_fp8(src[m], src[16 + m], src[32 + m], src[48 + m]);
        uint4* dst = (uint4*)(out + r * 128 + kt * 64);
#pragma unroll
        for (int j = 0; j < 4; ++j)
            dst[j] = make_uint4(dw[4 * j], dw[4 * j + 1], dw[4 * j + 2], dw[4 * j + 3]);
    }
}

// ---------- prep: Wpack = fp8(A - B), register-path layout with PERMUTED k-order ----------
__global__ __launch_bounds__(256) void wpack_all_kernel(const float* __restrict__ A0,
                                                        const float* __restrict__ B0,
                                                        const float* __restrict__ A1,
                                                        const float* __restrict__ B1,
                                                        const float* __restrict__ A2,
                                                        const float* __restrict__ B2,
                                                        unsigned long long* __restrict__ W0,
                                                        unsigned long long* __restrict__ W1,
                                                        unsigned long long* __restrict__ W2) {
    int idx = blockIdx.x * 256 + threadIdx.x;
    const float *A, *B; unsigned long long* W; int KD, u;
    if (idx < 8192)       { A = A0; B = B0; W = W0; KD = 128; u = idx; }
    else if (idx < 40960) { A = A1; B = B1; W = W1; KD = 512; u = idx - 8192; }
    else                  { A = A2; B = B2; W = W2; KD = 512; u = idx - 40960; if (u >= 32768) return; }
    int F = (KD / 64) * 8;
    int lane = u & 63;
    int f = (u >> 6) % F;
    int wid = u / (64 * F);
    int ks = f >> 3, fn = (f >> 1) & 3, s = f & 1;
    int ln15 = lane & 15, lg = lane >> 4;
    int row = wid * 64 + fn * 16 + ln15;
    int c0 = s * 8 + lg * 2;
    const float* sa = A + (long)row * KD + ks * 64;
    const float* sb = B + (long)row * KD + ks * 64;
    unsigned lo = pack4_fp8(sa[c0] - sb[c0], sa[16 + c0] - sb[16 + c0],
                            sa[32 + c0] - sb[32 + c0], sa[48 + c0] - sb[48 + c0]);
    unsigned hi = pack4_fp8(sa[c0 + 1] - sb[c0 + 1], sa[17 + c0] - sb[17 + c0],
                            sa[33 + c0] - sb[33 + c0], sa[49 + c0] - sb[49 + c0]);
    W[u] = ((unsigned long long)hi << 32) | lo;
}

// ---------- colsum of in_set (fp32, deterministic 2-stage) ----------
__global__ __launch_bounds__(256) void colsum_in_kernel(const float* __restrict__ in,
                                                        float* __restrict__ parts) {
    __shared__ float sh[256];
    int t = threadIdx.x, blk = blockIdx.x;
    int c = t & 127, half = t >> 7;
    long rbeg = (long)blk * 196 + half;
    long rend = (long)(blk + 1) * 196; if (rend > NPTS) rend = NPTS;
    float s = 0.f;
    for (long r = rbeg; r < rend; r += 2) s += in[r * 128 + c];
    sh[t] = s;
    __syncthreads();
    if (t < 128) parts[blk * 128 + t] = sh[t] + sh[t + 128];
}

// ---------- generic partial reduce: parts[nparts][width] -> out[grid][width] ----------
__global__ void part_reduceW_kernel(const float* __restrict__ parts, int nparts, int width,
                                    int op, float* __restrict__ out) {
    int g = blockIdx.x, t = threadIdx.x;
    int chunk = (nparts + gridDim.x - 1) / gridDim.x;
    int b0 = g * chunk, b1 = b0 + chunk; if (b1 > nparts) b1 = nparts;
    float s = 0.f;  // identity 0 valid for max too: values are post-relu >= 0
    for (int b = b0; b < b1; ++b) {
        float v = parts[(long)b * width + t];
        s = (op == 0) ? (s + v) : fmaxf(s, v);
    }
    out[(long)g * width + t] = s;
}

// ---------- fold 8 partial rows (compile-time unrolled) + GEMV ----------
__global__ __launch_bounds__(64) void gemv_fold_kernel(const float* __restrict__ p3, int dsum,
                                                       const float* __restrict__ Bm,
                                                       const float* __restrict__ bias, int op,
                                                       float* __restrict__ out) {
    int j = blockIdx.x, t = threadIdx.x;
    float acc = 0.f;
    for (int d = t; d < dsum; d += 64) {
        float s = 0.f;
#pragma unroll
        for (int g = 0; g < 8; ++g) {
            float v = p3[(long)g * dsum + d];
            s = (op == 0) ? (s + v) : fmaxf(s, v);
        }
        acc += s * Bm[(long)j * dsum + d];
    }
#pragma unroll
    for (int m = 32; m >= 1; m >>= 1) acc += __shfl_down(acc, m);
    if (t == 0) out[j] = acc + (bias ? bias[j] : 0.0f);
}

// ---------- fused layer (fp8, zero-sync K-loop + W reg-pipeline, 8 waves x 64 cols) --------
// Identical to R16's layer kernel (row-major h + W register double-buffer).
template<int KD, bool STORE, int REDOP>  // REDOP 0=sum, 1=max
__global__ __launch_bounds__(512, 4)
void layer_kernel(const unsigned char* __restrict__ Xp, const unsigned long long* __restrict__ Wp,
                  const float* __restrict__ cvec, const float* __restrict__ gvec,
                  const float* __restrict__ bvec, unsigned char* __restrict__ Hout,
                  float* __restrict__ red_out) {
    static_assert(KD % 64 == 0, "");
    constexpr int NK = KD / 64;
    __shared__ __align__(128) char smem[NK * 4096];   // X [NK][64][64] fp8; epilogue reuse

    const int t = threadIdx.x;
    const int lane = t & 63;
    const int wid = t >> 6;          // 0..7 : this wave's 64-col slice
    const int ln15 = lane & 15;
    const int lg = lane >> 4;        // 0..3
    const long row0 = (long)blockIdx.x * 64;

    f32x4 acc[4][4];
#pragma unroll
    for (int i = 0; i < 4; ++i)
#pragma unroll
        for (int j = 0; j < 4; ++j) acc[i][j] = (f32x4){0.f, 0.f, 0.f, 0.f};

    // ---- X prologue: stage the whole row-tile (row-major source) ----
    if (t < 256) {
        const int sr = t >> 2;       // 0..63
        const int ss = t & 3;
        const char* Xsrc = (const char*)Xp + (row0 + sr) * KD + ((ss ^ ((sr >> 1) & 3)) * 16);
#pragma unroll
        for (int kt = 0; kt < NK; ++kt)
            async_copy16(Xsrc + kt * 64, smem + kt * 4096 + t * 16);
    }
    __syncthreads();   // compiler emits vmcnt(0)+barrier: all X resident from here on

    // LDS read: row r, k-subtile sub, k-group lg -> swizzled slot (same involution as staging)
#define RD8X(BASE, r, sub) (*(const long*)((BASE) + (r) * 64 + \
        (((((sub) * 2 + (lg >> 1)) ^ (((r) >> 1) & 3)) * 16) + (lg & 1) * 8)))

    // ---- zero-sync K-loop with explicit W double-buffer ----
    const unsigned long long* Wq = Wp + (long)wid * (NK * 8) * 64 + lane;
    long wbuf[2][8];
#pragma unroll
    for (int f = 0; f < 8; ++f) wbuf[0][f] = (long)Wq[f * 64];

#pragma unroll
    for (int ks = 0; ks < NK; ++ks) {
        // prefetch next kstep's W fragments before this kstep's MFMAs (ks literal => static idx)
        if (ks + 1 < NK) {
#pragma unroll
            for (int f = 0; f < 8; ++f)
                wbuf[(ks + 1) & 1][f] = (long)Wq[((ks + 1) * 8 + f) * 64];
        }
        const char* Xs = smem + ks * 4096;
        long a0[4], a1[4];
#pragma unroll
        for (int fm = 0; fm < 4; ++fm) {
            int r = fm * 16 + ln15;
            a0[fm] = RD8X(Xs, r, 0);
            a1[fm] = RD8X(Xs, r, 1);
        }
#pragma unroll
        for (int fn = 0; fn < 4; ++fn) {
#pragma unroll
            for (int fm = 0; fm < 4; ++fm)
                acc[fm][fn] = __builtin_amdgcn_mfma_f32_16x16x32_fp8_fp8(
                    a0[fm], wbuf[ks & 1][fn * 2 + 0], acc[fm][fn], 0, 0, 0);
#pragma unroll
            for (int fm = 0; fm < 4; ++fm)
                acc[fm][fn] = __builtin_amdgcn_mfma_f32_16x16x32_fp8_fp8(
                    a1[fm], wbuf[ks & 1][fn * 2 + 1], acc[fm][fn], 0, 0, 0);
        }
    }
#undef RD8X
    __syncthreads();   // before epilogue reuses LDS

    // ---------------- epilogue (reuses LDS; needs 4608B <= NK*4096 since NK>=2) ----------------
    float* lnred_s = (float*)smem;            // [64][8] = 2048B
    float* lnred_q = (float*)(smem + 2048);   // [64][8] = 2048B
    float* lnmv    = (float*)(smem + 4096);   // [64][2] = 512B

    const int cbase = wid * 64 + ln15;
    float cv[4], gv[4], bv[4];
#pragma unroll
    for (int fn = 0; fn < 4; ++fn) {
        int col = cbase + fn * 16;
        cv[fn] = cvec[col]; gv[fn] = gvec[col]; bv[fn] = bvec[col];
    }

    // add the broadcast c-vector (fp32-exact common term)
#pragma unroll
    for (int fm = 0; fm < 4; ++fm)
#pragma unroll
        for (int fn = 0; fn < 4; ++fn) acc[fm][fn] += cv[fn];

    // per-row sum / sumsq over this wave's 64 cols (shfl tree within 16-lane group)
    float rs[16], rq[16];
#pragma unroll
    for (int fm = 0; fm < 4; ++fm)
#pragma unroll
        for (int j = 0; j < 4; ++j) {
            float s = 0.f, q = 0.f;
#pragma unroll
            for (int fn = 0; fn < 4; ++fn) {
                float x = acc[fm][fn][j];
                s += x; q += x * x;
            }
            rs[fm * 4 + j] = s; rq[fm * 4 + j] = q;
        }
#pragma unroll
    for (int m = 1; m < 16; m <<= 1)
#pragma unroll
        for (int i = 0; i < 16; ++i) {
            rs[i] += __shfl_xor(rs[i], m);
            rq[i] += __shfl_xor(rq[i], m);
        }
    if (ln15 == 0) {
#pragma unroll
        for (int fm = 0; fm < 4; ++fm)
#pragma unroll
            for (int j = 0; j < 4; ++j) {
                int row = fm * 16 + lg * 4 + j;
                lnred_s[row * 8 + wid] = rs[fm * 4 + j];
                lnred_q[row * 8 + wid] = rq[fm * 4 + j];
            }
    }
    __syncthreads();
    if (t < 64) {
        float s = 0.f, q = 0.f;
#pragma unroll
        for (int w = 0; w < 8; ++w) { s += lnred_s[t * 8 + w]; q += lnred_q[t * 8 + w]; }
        float mu = s * (1.0f / 512.0f);
        float var = q * (1.0f / 512.0f) - mu * mu;
        lnmv[t * 2] = mu;
        lnmv[t * 2 + 1] = rsqrtf(var + EPSV);
    }
    __syncthreads();

    // normalize + relu + coalesced permuted row-major store ; invalid rows forced to 0
#pragma unroll
    for (int fm = 0; fm < 4; ++fm)
#pragma unroll
        for (int j = 0; j < 4; ++j) {
            int rloc = fm * 16 + lg * 4 + j;
            long rglob = row0 + rloc;
            bool ok = rglob < NPTS;
            float mu = lnmv[rloc * 2], rstd = lnmv[rloc * 2 + 1];
#pragma unroll
            for (int fn = 0; fn < 4; ++fn) {
                float y = fmaxf((acc[fm][fn][j] - mu) * rstd * gv[fn] + bv[fn], 0.0f);
                acc[fm][fn][j] = ok ? y : 0.0f;
            }
            if (STORE) {
                unsigned u = pack4_fp8(acc[fm][0][j], acc[fm][1][j], acc[fm][2][j], acc[fm][3][j]);
                *(unsigned*)(Hout + rglob * DHID + wid * 64 + ln15 * 4) = u;
            }
        }

    // column partials over the block's 64 rows (sum or max); cols disjoint across waves
    float cp[4];
#pragma unroll
    for (int fn = 0; fn < 4; ++fn) {
        float p = 0.f;
#pragma unroll
        for (int fm = 0; fm < 4; ++fm)
#pragma unroll
            for (int j = 0; j < 4; ++j) {
                float v = acc[fm][fn][j];
                p = (REDOP == 0) ? (p + v) : fmaxf(p, v);
            }
        cp[fn] = p;
    }
#pragma unroll
    for (int m = 16; m < 64; m <<= 1)
#pragma unroll
        for (int fn = 0; fn < 4; ++fn) {
            float o = __shfl_xor(cp[fn], m);
            cp[fn] = (REDOP == 0) ? (cp[fn] + o) : fmaxf(cp[fn], o);
        }
    if (lane < 16) {
#pragma unroll
        for (int fn = 0; fn < 4; ++fn)
            red_out[(long)blockIdx.x * 512 + wid * 64 + fn * 16 + lane] = cp[fn];
    }
}

extern "C" void kernel_launch(void* const* d_in, const int* in_sizes, int n_in,
                              void* d_out, int out_size, void* d_ws, size_t ws_size,
                              hipStream_t stream) {
    const float* in_set = (const float*)d_in[0];
    const float* A0 = (const float*)d_in[1];
    const float* B0 = (const float*)d_in[2];
    const float* A1 = (const float*)d_in[3];
    const float* B1 = (const float*)d_in[4];
    const float* A2 = (const float*)d_in[5];
    const float* B2 = (const float*)d_in[6];
    const float* ga = (const float*)d_in[7];
    const float* be = (const float*)d_in[8];
    const float* ow = (const float*)d_in[9];
    const float* ob = (const float*)d_in[10];
    float* outp = (float*)d_out;
    char* ws = (char*)d_ws;

    unsigned char* in_f8 = (unsigned char*)(ws + OFF_INBF);
    unsigned long long* W0p = (unsigned long long*)(ws + OFF_W0);
    unsigned long long* W1p = (unsigned long long*)(ws + OFF_W1);
    unsigned long long* W2p = (unsigned long long*)(ws + OFF_W2);
    float* c0 = (float*)(ws + OFF_C0);
    float* c1 = (float*)(ws + OFF_C1);
    float* c2 = (float*)(ws + OFF_C2);
    float* parts = (float*)(ws + OFF_PARTS);
    float* parts2 = (float*)(ws + OFF_PARTS2);
    float* parts3 = (float*)(ws + OFF_PARTS3);
    unsigned char* h1 = (unsigned char*)(ws + OFF_H1);
    unsigned char* h2 = (unsigned char*)(ws + OFF_H2);

    const int nblk = (NPTS + 63) / 64;  // 1563

    cvt_pack_kernel<<<1024, 256, 0, stream>>>(in_set, in_f8);
    wpack_all_kernel<<<288, 256, 0, stream>>>(A0, B0, A1, B1, A2, B2, W0p, W1p, W2p);

    // c0 = colsum(in_set) @ B0^T  (all fp32 — the numerically critical path), wide+shallow
    colsum_in_kernel<<<512, 256, 0, stream>>>(in_set, parts);                       // [512][128]
    part_reduceW_kernel<<<64, 128, 0, stream>>>(parts, 512, 128, 0, parts2);        // [64][128]
    part_reduceW_kernel<<<8, 128, 0, stream>>>(parts2, 64, 128, 0, parts3);         // [8][128]
    gemv_fold_kernel<<<512, 64, 0, stream>>>(parts3, 128, B0, nullptr, 0, c0);

    layer_kernel<128, true, 0><<<nblk, 512, 0, stream>>>(in_f8, W0p, c0, ga, be, h1, parts);
    part_reduceW_kernel<<<64, 512, 0, stream>>>(parts, nblk, 512, 0, parts2);
    part_reduceW_kernel<<<8, 512, 0, stream>>>(parts2, 64, 512, 0, parts3);
    gemv_fold_kernel<<<512, 64, 0, stream>>>(parts3, 512, B1, nullptr, 0, c1);

    layer_kernel<512, true, 0><<<nblk, 512, 0, stream>>>(h1, W1p, c1, ga, be, h2, parts);
    part_reduceW_kernel<<<64, 512, 0, stream>>>(parts, nblk, 512, 0, parts2);
    part_reduceW_kernel<<<8, 512, 0, stream>>>(parts2, 64, 512, 0, parts3);
    gemv_fold_kernel<<<512, 64, 0, stream>>>(parts3, 512, B2, nullptr, 0, c2);

    // layer 2: no h3 store; fused column-max partials; final = (max-fold) @ ow^T + ob
    layer_kernel<512, false, 1><<<nblk, 512, 0, stream>>>(h2, W2p, c2, ga, be, nullptr, parts);
    part_reduceW_kernel<<<64, 512, 0, stream>>>(parts, nblk, 512, 1, parts2);
    part_reduceW_kernel<<<8, 512, 0, stream>>>(parts2, 64, 512, 1, parts3);
    gemv_fold_kernel<<<256, 64, 0, stream>>>(parts3, 512, ow, ob, 1, outp);
}

// Round 18
// 297.779 us; speedup vs baseline: 2.3191x; 1.0088x over previous
//
#include <hip/hip_runtime.h>
#include <hip/hip_bf16.h>

#define NPTS 100000
#define NPTS_PAD 100096
#define DHID 512
#define EPSV 1e-5f

typedef __attribute__((ext_vector_type(4))) float f32x4;

// ---- workspace layout (bytes) ----
// X/H ROW-MAJOR fp8 e4m3: [NPTS_PAD][KD]. Within each 64B group g of a row, position p
// holds logical col g*64 + (p&3)*16 + (p>>2). Layer stores are packed dwords; each thread's
// (fm,j) pair of dword stores covers one full 128B line.
// W register-path fp8: Wpack[wv(4)][frag(NK*16)][lane(64)] u64, frag = ks*16 + fn*2 + s;
//   byte q = (A-B)[wv*128+fn*16+ln15][ks*64 + (q&3)*16 + s*8 + lg*2 + (q>>2)]
#define OFF_INBF   0UL            // 100096*128 = 12,812,288
#define OFF_W0     12812288UL     // 4*32*64*8  = 65,536
#define OFF_W1     12877824UL     // 4*128*64*8 = 262,144
#define OFF_W2     13139968UL     // 262,144
#define OFF_C0     13402112UL     // 512*4 (pad to 2048)
#define OFF_C1     13404160UL
#define OFF_C2     13406208UL
#define OFF_PARTS  13408256UL     // 1563*512*4 = 3,201,024
#define OFF_PARTS2 16609280UL     // 64*512*4 = 131,072
#define OFF_PARTS3 16740352UL     // 8*512*4 = 16,384
#define OFF_H1     16756736UL     // 100096*512 = 51,249,152
#define OFF_H2     68005888UL     // 51,249,152  (end 119,255,040)

typedef const __attribute__((address_space(1))) unsigned int* gp_t;
typedef __attribute__((address_space(3))) unsigned int* lp_t;

__device__ __forceinline__ void async_copy16(const void* g, void* l) {
    __builtin_amdgcn_global_load_lds((gp_t)g, (lp_t)l, 16, 0, 0);
}

// pack 4 floats -> 4 fp8 e4m3 bytes (RNE); a->byte0 .. d->byte3
__device__ __forceinline__ unsigned pack4_fp8(float a, float b, float c, float d) {
    unsigned v = (unsigned)__builtin_amdgcn_cvt_pk_fp8_f32(a, b, 0, false);
    v = (unsigned)__builtin_amdgcn_cvt_pk_fp8_f32(c, d, (int)v, true);
    return v;
}

// ---------- prep: fp32 [NPTS][128] -> fp8 row-major [NPTS_PAD][128] (PERMUTED groups) ------
__global__ __launch_bounds__(256) void cvt_pack_kernel(const float* __restrict__ in,
                                                       unsigned char* __restrict__ out) {
    long total = (long)NPTS * 2;
    long stride = (long)gridDim.x * blockDim.x;
    for (long idx = (long)blockIdx.x * blockDim.x + threadIdx.x; idx < total; idx += stride) {
        int kt = (int)(idx / NPTS);
        long r = idx - (long)kt * NPTS;
        const float* src = in + r * 128 + kt * 64;
        unsigned dw[16];
#pragma unroll
        for (int m = 0; m < 16; ++m)
            dw[m] = pack4_fp8(src[m], src[16 + m], src[32 + m], src[48 + m]);
        uint4* dst = (uint4*)(out + r * 128 + kt * 64);
#pragma unroll
        for (int j = 0; j < 4; ++j)
            dst[j] = make_uint4(dw[4 * j], dw[4 * j + 1], dw[4 * j + 2], dw[4 * j + 3]);
    }
}

// ---------- prep: Wpack = fp8(A - B), 4-wave slice layout, PERMUTED k-order ----------
// u = ((wv*NK + ks)*16 + fn*2 + s)*64 + lane ; fn = 0..7 ; F = NK*16
// W0: 4*2*16*64 = 8192 u64 ; W1/W2: 4*8*16*64 = 32768 each ; total 73728 = 288 x 256
__global__ __launch_bounds__(256) void wpack_all_kernel(const float* __restrict__ A0,
                                                        const float* __restrict__ B0,
                                                        const float* __restrict__ A1,
                                                        const float* __restrict__ B1,
                                                        const float* __restrict__ A2,
                                                        const float* __restrict__ B2,
                                                        unsigned long long* __restrict__ W0,
                                                        unsigned long long* __restrict__ W1,
                                                        unsigned long long* __restrict__ W2) {
    int idx = blockIdx.x * 256 + threadIdx.x;
    const float *A, *B; unsigned long long* W; int NK, u;
    if (idx < 8192)       { A = A0; B = B0; W = W0; NK = 2; u = idx; }
    else if (idx < 40960) { A = A1; B = B1; W = W1; NK = 8; u = idx - 8192; }
    else                  { A = A2; B = B2; W = W2; NK = 8; u = idx - 40960; if (u >= 32768) return; }
    int KD = NK * 64;
    int lane = u & 63;
    int rest = u >> 6;
    int s = rest & 1;
    int fn = (rest >> 1) & 7;
    int ks = (rest >> 4) % NK;
    int wv = (rest >> 4) / NK;
    int ln15 = lane & 15, lg = lane >> 4;
    int row = wv * 128 + fn * 16 + ln15;
    int c0 = s * 8 + lg * 2;
    const float* sa = A + (long)row * KD + ks * 64;
    const float* sb = B + (long)row * KD + ks * 64;
    unsigned lo = pack4_fp8(sa[c0] - sb[c0], sa[16 + c0] - sb[16 + c0],
                            sa[32 + c0] - sb[32 + c0], sa[48 + c0] - sb[48 + c0]);
    unsigned hi = pack4_fp8(sa[c0 + 1] - sb[c0 + 1], sa[17 + c0] - sb[17 + c0],
                            sa[33 + c0] - sb[33 + c0], sa[49 + c0] - sb[49 + c0]);
    W[u] = ((unsigned long long)hi << 32) | lo;
}

// ---------- colsum of in_set (fp32, deterministic 2-stage) ----------
__global__ __launch_bounds__(256) void colsum_in_kernel(const float* __restrict__ in,
                                                        float* __restrict__ parts) {
    __shared__ float sh[256];
    int t = threadIdx.x, blk = blockIdx.x;
    int c = t & 127, half = t >> 7;
    long rbeg = (long)blk * 196 + half;
    long rend = (long)(blk + 1) * 196; if (rend > NPTS) rend = NPTS;
    float s = 0.f;
    for (long r = rbeg; r < rend; r += 2) s += in[r * 128 + c];
    sh[t] = s;
    __syncthreads();
    if (t < 128) parts[blk * 128 + t] = sh[t] + sh[t + 128];
}

// ---------- generic partial reduce: parts[nparts][width] -> out[grid][width] ----------
__global__ void part_reduceW_kernel(const float* __restrict__ parts, int nparts, int width,
                                    int op, float* __restrict__ out) {
    int g = blockIdx.x, t = threadIdx.x;
    int chunk = (nparts + gridDim.x - 1) / gridDim.x;
    int b0 = g * chunk, b1 = b0 + chunk; if (b1 > nparts) b1 = nparts;
    float s = 0.f;  // identity 0 valid for max too: values are post-relu >= 0
    for (int b = b0; b < b1; ++b) {
        float v = parts[(long)b * width + t];
        s = (op == 0) ? (s + v) : fmaxf(s, v);
    }
    out[(long)g * width + t] = s;
}

// ---------- fold 8 partial rows (compile-time unrolled) + GEMV ----------
__global__ __launch_bounds__(64) void gemv_fold_kernel(const float* __restrict__ p3, int dsum,
                                                       const float* __restrict__ Bm,
                                                       const float* __restrict__ bias, int op,
                                                       float* __restrict__ out) {
    int j = blockIdx.x, t = threadIdx.x;
    float acc = 0.f;
    for (int d = t; d < dsum; d += 64) {
        float s = 0.f;
#pragma unroll
        for (int g = 0; g < 8; ++g) {
            float v = p3[(long)g * dsum + d];
            s = (op == 0) ? (s + v) : fmaxf(s, v);
        }
        acc += s * Bm[(long)j * dsum + d];
    }
#pragma unroll
    for (int m = 32; m >= 1; m >>= 1) acc += __shfl_down(acc, m);
    if (t == 0) out[j] = acc + (bias ? bias[j] : 0.0f);
}

// ---------- fused layer (fp8, R11 champion geometry + pipelined X + packed stores) ----------
// BM=64, BN=512, 256 threads = 4 waves, wave wv owns cols [wv*128, wv*128+128). acc[4][8].
//  - X: per-kt-plane pipelined staging (write-once LDS => no WAR): per kstep ONE
//    global_load_lds (plane ks+3), counted vmcnt(2/1/0) + raw s_barrier, ZERO drains.
//  - W: direct global->register u64 loads from Wpack (contiguous 512B/wave-inst, L2-hot).
//  - Store: row-major + permuted groups -> 2 packed dword stores per (fm,j); the pair covers
//    one full 128B line (R11's clean-WRITE geometry, 4x fewer store insts).
template<int KD, bool STORE, int REDOP>  // REDOP 0=sum, 1=max
__global__ __launch_bounds__(256, 2)
void layer_kernel(const unsigned char* __restrict__ Xp, const unsigned long long* __restrict__ Wp,
                  const float* __restrict__ cvec, const float* __restrict__ gvec,
                  const float* __restrict__ bvec, unsigned char* __restrict__ Hout,
                  float* __restrict__ red_out) {
    static_assert(KD % 64 == 0, "");
    constexpr int NK = KD / 64;
    __shared__ __align__(128) char smem[NK * 4096];   // X [NK][64][64] fp8; epilogue reuse

    const int t = threadIdx.x;
    const int lane = t & 63;
    const int wv = t >> 6;           // 0..3 : this wave's 128-col slice
    const int ln15 = lane & 15;
    const int lg = lane >> 4;        // 0..3
    const long row0 = (long)blockIdx.x * 64;

    f32x4 acc[4][8];
#pragma unroll
    for (int i = 0; i < 4; ++i)
#pragma unroll
        for (int j = 0; j < 8; ++j) acc[i][j] = (f32x4){0.f, 0.f, 0.f, 0.f};

    // ---- X staging geometry: thread t stages 16B of row sr, swizzled slot ss, per plane ----
    const int sr = t >> 2;           // 0..63
    const int ss = t & 3;
    const char* Xsrc = (const char*)Xp + (row0 + sr) * KD + ((ss ^ ((sr >> 1) & 3)) * 16);
    auto stage_x = [&](int kt) {
        async_copy16(Xsrc + kt * 64, smem + kt * 4096 + t * 16);
    };

    // prologue: up to 3 planes in flight
    stage_x(0);
    if (NK > 1) stage_x(1);
    if (NK > 2) stage_x(2);

    // LDS read: row r, k-subtile sub, k-group lg -> swizzled slot (matches staging involution)
#define RD8X(BASE, r, sub) (*(const long*)((BASE) + (r) * 64 + \
        (((((sub) * 2 + (lg >> 1)) ^ (((r) >> 1) & 3)) * 16) + (lg & 1) * 8)))

    // ---- K-loop: counted-vmcnt plane pipeline; W direct-to-register ----
    const unsigned long long* Wq = Wp + (long)wv * (NK * 16) * 64 + lane;
#pragma unroll
    for (int ks = 0; ks < NK; ++ks) {
        if (ks < NK - 2)       asm volatile("s_waitcnt vmcnt(2)" ::: "memory");
        else if (ks == NK - 2) asm volatile("s_waitcnt vmcnt(1)" ::: "memory");
        else                   asm volatile("s_waitcnt vmcnt(0)" ::: "memory");
        __builtin_amdgcn_s_barrier();
        __builtin_amdgcn_sched_barrier(0);
        if (ks + 3 < NK) stage_x(ks + 3);   // write-once plane: no WAR, no second barrier

        const char* Xs = smem + ks * 4096;
        long a0[4], a1[4];
#pragma unroll
        for (int fm = 0; fm < 4; ++fm) {
            int r = fm * 16 + ln15;
            a0[fm] = RD8X(Xs, r, 0);
            a1[fm] = RD8X(Xs, r, 1);
        }
#pragma unroll
        for (int fn = 0; fn < 8; ++fn) {
            long w0 = (long)Wq[(ks * 16 + fn * 2 + 0) * 64];
            long w1 = (long)Wq[(ks * 16 + fn * 2 + 1) * 64];
#pragma unroll
            for (int fm = 0; fm < 4; ++fm)
                acc[fm][fn] = __builtin_amdgcn_mfma_f32_16x16x32_fp8_fp8(a0[fm], w0, acc[fm][fn], 0, 0, 0);
#pragma unroll
            for (int fm = 0; fm < 4; ++fm)
                acc[fm][fn] = __builtin_amdgcn_mfma_f32_16x16x32_fp8_fp8(a1[fm], w1, acc[fm][fn], 0, 0, 0);
        }
    }
#undef RD8X
    __syncthreads();   // before epilogue reuses LDS

    // ---------------- epilogue (reuses LDS; 2560B <= NK*4096) ----------------
    float* lnred_s = (float*)smem;            // [64][4]
    float* lnred_q = (float*)(smem + 1024);   // [64][4]
    float* lnmv    = (float*)(smem + 2048);   // [64][2]

    const int cbase = wv * 128 + ln15;
    float cv[8], gv[8], bv[8];
#pragma unroll
    for (int fn = 0; fn < 8; ++fn) {
        int col = cbase + fn * 16;
        cv[fn] = cvec[col]; gv[fn] = gvec[col]; bv[fn] = bvec[col];
    }

    // add the broadcast c-vector (fp32-exact common term)
#pragma unroll
    for (int fm = 0; fm < 4; ++fm)
#pragma unroll
        for (int fn = 0; fn < 8; ++fn) acc[fm][fn] += cv[fn];

    // per-row sum / sumsq over this wave's 128 cols (shfl tree within 16-lane group)
    float rs[16], rq[16];
#pragma unroll
    for (int fm = 0; fm < 4; ++fm)
#pragma unroll
        for (int j = 0; j < 4; ++j) {
            float s = 0.f, q = 0.f;
#pragma unroll
            for (int fn = 0; fn < 8; ++fn) {
                float x = acc[fm][fn][j];
                s += x; q += x * x;
            }
            rs[fm * 4 + j] = s; rq[fm * 4 + j] = q;
        }
#pragma unroll
    for (int m = 1; m < 16; m <<= 1)
#pragma unroll
        for (int i = 0; i < 16; ++i) {
            rs[i] += __shfl_xor(rs[i], m);
            rq[i] += __shfl_xor(rq[i], m);
        }
    if (ln15 == 0) {
#pragma unroll
        for (int fm = 0; fm < 4; ++fm)
#pragma unroll
            for (int j = 0; j < 4; ++j) {
                int row = fm * 16 + lg * 4 + j;
                lnred_s[row * 4 + wv] = rs[fm * 4 + j];
                lnred_q[row * 4 + wv] = rq[fm * 4 + j];
            }
    }
    __syncthreads();
    if (t < 64) {
        float s = lnred_s[t * 4] + lnred_s[t * 4 + 1] + lnred_s[t * 4 + 2] + lnred_s[t * 4 + 3];
        float q = lnred_q[t * 4] + lnred_q[t * 4 + 1] + lnred_q[t * 4 + 2] + lnred_q[t * 4 + 3];
        float mu = s * (1.0f / 512.0f);
        float var = q * (1.0f / 512.0f) - mu * mu;
        lnmv[t * 2] = mu;
        lnmv[t * 2 + 1] = rsqrtf(var + EPSV);
    }
    __syncthreads();

    // normalize + relu + packed row-major store (2 dwords = one full 128B line per thread)
#pragma unroll
    for (int fm = 0; fm < 4; ++fm)
#pragma unroll
        for (int j = 0; j < 4; ++j) {
            int rloc = fm * 16 + lg * 4 + j;
            long rglob = row0 + rloc;
            bool ok = rglob < NPTS;
            float mu = lnmv[rloc * 2], rstd = lnmv[rloc * 2 + 1];
#pragma unroll
            for (int fn = 0; fn < 8; ++fn) {
                float y = fmaxf((acc[fm][fn][j] - mu) * rstd * gv[fn] + bv[fn], 0.0f);
                acc[fm][fn][j] = ok ? y : 0.0f;
            }
            if (STORE) {
                unsigned ulo = pack4_fp8(acc[fm][0][j], acc[fm][1][j], acc[fm][2][j], acc[fm][3][j]);
                unsigned uhi = pack4_fp8(acc[fm][4][j], acc[fm][5][j], acc[fm][6][j], acc[fm][7][j]);
                char* base = (char*)Hout + rglob * DHID + wv * 128 + ln15 * 4;
                *(unsigned*)(base) = ulo;        // group wv*2   : fn 0..3
                *(unsigned*)(base + 64) = uhi;   // group wv*2+1 : fn 4..7
            }
        }

    // column partials over the block's 64 rows (sum or max); cols disjoint across waves
    float cp[8];
#pragma unroll
    for (int fn = 0; fn < 8; ++fn) {
        float p = 0.f;
#pragma unroll
        for (int fm = 0; fm < 4; ++fm)
#pragma unroll
            for (int j = 0; j < 4; ++j) {
                float v = acc[fm][fn][j];
                p = (REDOP == 0) ? (p + v) : fmaxf(p, v);
            }
        cp[fn] = p;
    }
#pragma unroll
    for (int m = 16; m < 64; m <<= 1)
#pragma unroll
        for (int fn = 0; fn < 8; ++fn) {
            float o = __shfl_xor(cp[fn], m);
            cp[fn] = (REDOP == 0) ? (cp[fn] + o) : fmaxf(cp[fn], o);
        }
    if (lane < 16) {
#pragma unroll
        for (int fn = 0; fn < 8; ++fn)
            red_out[(long)blockIdx.x * 512 + wv * 128 + fn * 16 + lane] = cp[fn];
    }
}

extern "C" void kernel_launch(void* const* d_in, const int* in_sizes, int n_in,
                              void* d_out, int out_size, void* d_ws, size_t ws_size,
                              hipStream_t stream) {
    const float* in_set = (const float*)d_in[0];
    const float* A0 = (const float*)d_in[1];
    const float* B0 = (const float*)d_in[2];
    const float* A1 = (const float*)d_in[3];
    const float* B1 = (const float*)d_in[4];
    const float* A2 = (const float*)d_in[5];
    const float* B2 = (const float*)d_in[6];
    const float* ga = (const float*)d_in[7];
    const float* be = (const float*)d_in[8];
    const float* ow = (const float*)d_in[9];
    const float* ob = (const float*)d_in[10];
    float* outp = (float*)d_out;
    char* ws = (char*)d_ws;

    unsigned char* in_f8 = (unsigned char*)(ws + OFF_INBF);
    unsigned long long* W0p = (unsigned long long*)(ws + OFF_W0);
    unsigned long long* W1p = (unsigned long long*)(ws + OFF_W1);
    unsigned long long* W2p = (unsigned long long*)(ws + OFF_W2);
    float* c0 = (float*)(ws + OFF_C0);
    float* c1 = (float*)(ws + OFF_C1);
    float* c2 = (float*)(ws + OFF_C2);
    float* parts = (float*)(ws + OFF_PARTS);
    float* parts2 = (float*)(ws + OFF_PARTS2);
    float* parts3 = (float*)(ws + OFF_PARTS3);
    unsigned char* h1 = (unsigned char*)(ws + OFF_H1);
    unsigned char* h2 = (unsigned char*)(ws + OFF_H2);

    const int nblk = (NPTS + 63) / 64;  // 1563

    cvt_pack_kernel<<<1024, 256, 0, stream>>>(in_set, in_f8);
    wpack_all_kernel<<<288, 256, 0, stream>>>(A0, B0, A1, B1, A2, B2, W0p, W1p, W2p);

    // c0 = colsum(in_set) @ B0^T  (all fp32 — the numerically critical path), wide+shallow
    colsum_in_kernel<<<512, 256, 0, stream>>>(in_set, parts);                       // [512][128]
    part_reduceW_kernel<<<64, 128, 0, stream>>>(parts, 512, 128, 0, parts2);        // [64][128]
    part_reduceW_kernel<<<8, 128, 0, stream>>>(parts2, 64, 128, 0, parts3);         // [8][128]
    gemv_fold_kernel<<<512, 64, 0, stream>>>(parts3, 128, B0, nullptr, 0, c0);

    layer_kernel<128, true, 0><<<nblk, 256, 0, stream>>>(in_f8, W0p, c0, ga, be, h1, parts);
    part_reduceW_kernel<<<64, 512, 0, stream>>>(parts, nblk, 512, 0, parts2);
    part_reduceW_kernel<<<8, 512, 0, stream>>>(parts2, 64, 512, 0, parts3);
    gemv_fold_kernel<<<512, 64, 0, stream>>>(parts3, 512, B1, nullptr, 0, c1);

    layer_kernel<512, true, 0><<<nblk, 256, 0, stream>>>(h1, W1p, c1, ga, be, h2, parts);
    part_reduceW_kernel<<<64, 512, 0, stream>>>(parts, nblk, 512, 0, parts2);
    part_reduceW_kernel<<<8, 512, 0, stream>>>(parts2, 64, 512, 0, parts3);
    gemv_fold_kernel<<<512, 64, 0, stream>>>(parts3, 512, B2, nullptr, 0, c2);

    // layer 2: no h3 store; fused column-max partials; final = (max-fold) @ ow^T + ob
    layer_kernel<512, false, 1><<<nblk, 256, 0, stream>>>(h2, W2p, c2, ga, be, nullptr, parts);
    part_reduceW_kernel<<<64, 512, 0, stream>>>(parts, nblk, 512, 1, parts2);
    part_reduceW_kernel<<<8, 512, 0, stream>>>(parts2, 64, 512, 1, parts3);
    gemv_fold_kernel<<<256, 64, 0, stream>>>(parts3, 512, ow, ob, 1, outp);
}

// Round 19
// 264.859 us; speedup vs baseline: 2.6073x; 1.1243x over previous
//
#include <hip/hip_runtime.h>
#include <hip/hip_bf16.h>

#define NPTS 100000
#define NPTS_PAD 100096
#define DHID 512
#define EPSV 1e-5f

typedef __attribute__((ext_vector_type(4))) float f32x4;

// ---- workspace layout (bytes) ----
// X/H ROW-MAJOR fp8 e4m3: [NPTS_PAD][KD]. Within each 64B group g of a row, position p
// holds logical col g*64 + (p&3)*16 + (p>>2). Layer stores are packed dwords; each thread's
// (fm,j) pair of dword stores covers one full 128B line.
// W register-path fp8: Wpack[wv(4)][frag(NK*16)][lane(64)] u64, frag = ks*16 + fn*2 + s;
//   byte q = (A-B)[wv*128+fn*16+ln15][ks*64 + (q&3)*16 + s*8 + lg*2 + (q>>2)]
#define OFF_INBF   0UL            // 100096*128 = 12,812,288
#define OFF_W0     12812288UL     // 4*32*64*8  = 65,536
#define OFF_W1     12877824UL     // 4*128*64*8 = 262,144
#define OFF_W2     13139968UL     // 262,144
#define OFF_C0     13402112UL     // 512*4 (pad to 2048)
#define OFF_C1     13404160UL
#define OFF_C2     13406208UL
#define OFF_PARTS  13408256UL     // 1563*512*4 = 3,201,024
#define OFF_PARTS2 16609280UL     // 64*512*4 = 131,072
#define OFF_PARTS3 16740352UL     // 8*512*4 = 16,384
#define OFF_H1     16756736UL     // 100096*512 = 51,249,152
#define OFF_H2     68005888UL     // 51,249,152  (end 119,255,040)

typedef const __attribute__((address_space(1))) unsigned int* gp_t;
typedef __attribute__((address_space(3))) unsigned int* lp_t;

__device__ __forceinline__ void async_copy16(const void* g, void* l) {
    __builtin_amdgcn_global_load_lds((gp_t)g, (lp_t)l, 16, 0, 0);
}

// pack 4 floats -> 4 fp8 e4m3 bytes (RNE); a->byte0 .. d->byte3
__device__ __forceinline__ unsigned pack4_fp8(float a, float b, float c, float d) {
    unsigned v = (unsigned)__builtin_amdgcn_cvt_pk_fp8_f32(a, b, 0, false);
    v = (unsigned)__builtin_amdgcn_cvt_pk_fp8_f32(c, d, (int)v, true);
    return v;
}

// ---------- prep: fp32 [NPTS][128] -> fp8 row-major [NPTS_PAD][128] (PERMUTED groups) ------
__global__ __launch_bounds__(256) void cvt_pack_kernel(const float* __restrict__ in,
                                                       unsigned char* __restrict__ out) {
    long total = (long)NPTS * 2;
    long stride = (long)gridDim.x * blockDim.x;
    for (long idx = (long)blockIdx.x * blockDim.x + threadIdx.x; idx < total; idx += stride) {
        int kt = (int)(idx / NPTS);
        long r = idx - (long)kt * NPTS;
        const float* src = in + r * 128 + kt * 64;
        unsigned dw[16];
#pragma unroll
        for (int m = 0; m < 16; ++m)
            dw[m] = pack4_fp8(src[m], src[16 + m], src[32 + m], src[48 + m]);
        uint4* dst = (uint4*)(out + r * 128 + kt * 64);
#pragma unroll
        for (int j = 0; j < 4; ++j)
            dst[j] = make_uint4(dw[4 * j], dw[4 * j + 1], dw[4 * j + 2], dw[4 * j + 3]);
    }
}

// ---------- prep: Wpack = fp8(A - B), 4-wave slice layout, PERMUTED k-order ----------
// u = ((wv*NK + ks)*16 + fn*2 + s)*64 + lane ; fn = 0..7 ; F = NK*16
__global__ __launch_bounds__(256) void wpack_all_kernel(const float* __restrict__ A0,
                                                        const float* __restrict__ B0,
                                                        const float* __restrict__ A1,
                                                        const float* __restrict__ B1,
                                                        const float* __restrict__ A2,
                                                        const float* __restrict__ B2,
                                                        unsigned long long* __restrict__ W0,
                                                        unsigned long long* __restrict__ W1,
                                                        unsigned long long* __restrict__ W2) {
    int idx = blockIdx.x * 256 + threadIdx.x;
    const float *A, *B; unsigned long long* W; int NK, u;
    if (idx < 8192)       { A = A0; B = B0; W = W0; NK = 2; u = idx; }
    else if (idx < 40960) { A = A1; B = B1; W = W1; NK = 8; u = idx - 8192; }
    else                  { A = A2; B = B2; W = W2; NK = 8; u = idx - 40960; if (u >= 32768) return; }
    int KD = NK * 64;
    int lane = u & 63;
    int rest = u >> 6;
    int s = rest & 1;
    int fn = (rest >> 1) & 7;
    int ks = (rest >> 4) % NK;
    int wv = (rest >> 4) / NK;
    int ln15 = lane & 15, lg = lane >> 4;
    int row = wv * 128 + fn * 16 + ln15;
    int c0 = s * 8 + lg * 2;
    const float* sa = A + (long)row * KD + ks * 64;
    const float* sb = B + (long)row * KD + ks * 64;
    unsigned lo = pack4_fp8(sa[c0] - sb[c0], sa[16 + c0] - sb[16 + c0],
                            sa[32 + c0] - sb[32 + c0], sa[48 + c0] - sb[48 + c0]);
    unsigned hi = pack4_fp8(sa[c0 + 1] - sb[c0 + 1], sa[17 + c0] - sb[17 + c0],
                            sa[33 + c0] - sb[33 + c0], sa[49 + c0] - sb[49 + c0]);
    W[u] = ((unsigned long long)hi << 32) | lo;
}

// ---------- colsum of in_set (fp32, deterministic 2-stage) ----------
__global__ __launch_bounds__(256) void colsum_in_kernel(const float* __restrict__ in,
                                                        float* __restrict__ parts) {
    __shared__ float sh[256];
    int t = threadIdx.x, blk = blockIdx.x;
    int c = t & 127, half = t >> 7;
    long rbeg = (long)blk * 196 + half;
    long rend = (long)(blk + 1) * 196; if (rend > NPTS) rend = NPTS;
    float s = 0.f;
    for (long r = rbeg; r < rend; r += 2) s += in[r * 128 + c];
    sh[t] = s;
    __syncthreads();
    if (t < 128) parts[blk * 128 + t] = sh[t] + sh[t + 128];
}

// ---------- generic partial reduce: parts[nparts][width] -> out[grid][width] ----------
__global__ void part_reduceW_kernel(const float* __restrict__ parts, int nparts, int width,
                                    int op, float* __restrict__ out) {
    int g = blockIdx.x, t = threadIdx.x;
    int chunk = (nparts + gridDim.x - 1) / gridDim.x;
    int b0 = g * chunk, b1 = b0 + chunk; if (b1 > nparts) b1 = nparts;
    float s = 0.f;  // identity 0 valid for max too: values are post-relu >= 0
    for (int b = b0; b < b1; ++b) {
        float v = parts[(long)b * width + t];
        s = (op == 0) ? (s + v) : fmaxf(s, v);
    }
    out[(long)g * width + t] = s;
}

// ---------- fold 8 partial rows (compile-time unrolled) + GEMV ----------
__global__ __launch_bounds__(64) void gemv_fold_kernel(const float* __restrict__ p3, int dsum,
                                                       const float* __restrict__ Bm,
                                                       const float* __restrict__ bias, int op,
                                                       float* __restrict__ out) {
    int j = blockIdx.x, t = threadIdx.x;
    float acc = 0.f;
    for (int d = t; d < dsum; d += 64) {
        float s = 0.f;
#pragma unroll
        for (int g = 0; g < 8; ++g) {
            float v = p3[(long)g * dsum + d];
            s = (op == 0) ? (s + v) : fmaxf(s, v);
        }
        acc += s * Bm[(long)j * dsum + d];
    }
#pragma unroll
    for (int m = 32; m >= 1; m >>= 1) acc += __shfl_down(acc, m);
    if (t == 0) out[j] = acc + (bias ? bias[j] : 0.0f);
}

// ---------- fused layer (fp8, R11 zero-sync structure + explicit W reg double-buffer) ------
// BM=64, BN=512, 256 threads = 4 waves, wave wv owns cols [wv*128, wv*128+128). acc[4][8].
//  - X staged into LDS ONCE (NK*4KB), one __syncthreads total (R11 champion structure:
//    NO barriers/waits/pins in the K-loop — every pipelined-staging variant regressed).
//  - W: explicit register double-buffer wbuf[2][16] (statically indexed under full unroll);
//    kstep ks+1's 16 L2-loads issue BEFORE ks's MFMA cluster. launch_bounds(256,2) gives a
//    256-VGPR budget: acc 128 + wbuf 64 + a-frags 16 + addr ~ 230 fits (R17's null was a
//    128-VGPR cap that silently dropped the buffer).
//  - Store: row-major + permuted groups -> 2 packed dword stores per (fm,j) = one 128B line.
template<int KD, bool STORE, int REDOP>  // REDOP 0=sum, 1=max
__global__ __launch_bounds__(256, 2)
void layer_kernel(const unsigned char* __restrict__ Xp, const unsigned long long* __restrict__ Wp,
                  const float* __restrict__ cvec, const float* __restrict__ gvec,
                  const float* __restrict__ bvec, unsigned char* __restrict__ Hout,
                  float* __restrict__ red_out) {
    static_assert(KD % 64 == 0, "");
    constexpr int NK = KD / 64;
    __shared__ __align__(128) char smem[NK * 4096];   // X [NK][64][64] fp8; epilogue reuse

    const int t = threadIdx.x;
    const int lane = t & 63;
    const int wv = t >> 6;           // 0..3 : this wave's 128-col slice
    const int ln15 = lane & 15;
    const int lg = lane >> 4;        // 0..3
    const long row0 = (long)blockIdx.x * 64;

    f32x4 acc[4][8];
#pragma unroll
    for (int i = 0; i < 4; ++i)
#pragma unroll
        for (int j = 0; j < 8; ++j) acc[i][j] = (f32x4){0.f, 0.f, 0.f, 0.f};

    // ---- X prologue: stage ALL NK planes once (zero-sync loop thereafter) ----
    {
        const int sr = t >> 2;       // 0..63
        const int ss = t & 3;
        const char* Xsrc = (const char*)Xp + (row0 + sr) * KD + ((ss ^ ((sr >> 1) & 3)) * 16);
#pragma unroll
        for (int kt = 0; kt < NK; ++kt)
            async_copy16(Xsrc + kt * 64, smem + kt * 4096 + t * 16);
    }
    __syncthreads();   // compiler emits vmcnt(0)+barrier: all X resident from here on

    // LDS read: row r, k-subtile sub, k-group lg -> swizzled slot (matches staging involution)
#define RD8X(BASE, r, sub) (*(const long*)((BASE) + (r) * 64 + \
        (((((sub) * 2 + (lg >> 1)) ^ (((r) >> 1) & 3)) * 16) + (lg & 1) * 8)))

    // ---- zero-sync K-loop with explicit W register double-buffer ----
    const unsigned long long* Wq = Wp + (long)wv * (NK * 16) * 64 + lane;
    long wbuf[2][16];
#pragma unroll
    for (int f = 0; f < 16; ++f) wbuf[0][f] = (long)Wq[f * 64];

#pragma unroll
    for (int ks = 0; ks < NK; ++ks) {
        // issue next kstep's 16 W loads first (ks literal => static wbuf index, rule #20)
        if (ks + 1 < NK) {
#pragma unroll
            for (int f = 0; f < 16; ++f)
                wbuf[(ks + 1) & 1][f] = (long)Wq[((ks + 1) * 16 + f) * 64];
        }
        const char* Xs = smem + ks * 4096;
        long a0[4], a1[4];
#pragma unroll
        for (int fm = 0; fm < 4; ++fm) {
            int r = fm * 16 + ln15;
            a0[fm] = RD8X(Xs, r, 0);
            a1[fm] = RD8X(Xs, r, 1);
        }
#pragma unroll
        for (int fn = 0; fn < 8; ++fn) {
#pragma unroll
            for (int fm = 0; fm < 4; ++fm)
                acc[fm][fn] = __builtin_amdgcn_mfma_f32_16x16x32_fp8_fp8(
                    a0[fm], wbuf[ks & 1][fn * 2 + 0], acc[fm][fn], 0, 0, 0);
#pragma unroll
            for (int fm = 0; fm < 4; ++fm)
                acc[fm][fn] = __builtin_amdgcn_mfma_f32_16x16x32_fp8_fp8(
                    a1[fm], wbuf[ks & 1][fn * 2 + 1], acc[fm][fn], 0, 0, 0);
        }
    }
#undef RD8X
    __syncthreads();   // before epilogue reuses LDS

    // ---------------- epilogue (reuses LDS; 2560B <= NK*4096) ----------------
    float* lnred_s = (float*)smem;            // [64][4]
    float* lnred_q = (float*)(smem + 1024);   // [64][4]
    float* lnmv    = (float*)(smem + 2048);   // [64][2]

    const int cbase = wv * 128 + ln15;
    float cv[8], gv[8], bv[8];
#pragma unroll
    for (int fn = 0; fn < 8; ++fn) {
        int col = cbase + fn * 16;
        cv[fn] = cvec[col]; gv[fn] = gvec[col]; bv[fn] = bvec[col];
    }

    // add the broadcast c-vector (fp32-exact common term)
#pragma unroll
    for (int fm = 0; fm < 4; ++fm)
#pragma unroll
        for (int fn = 0; fn < 8; ++fn) acc[fm][fn] += cv[fn];

    // per-row sum / sumsq over this wave's 128 cols (shfl tree within 16-lane group)
    float rs[16], rq[16];
#pragma unroll
    for (int fm = 0; fm < 4; ++fm)
#pragma unroll
        for (int j = 0; j < 4; ++j) {
            float s = 0.f, q = 0.f;
#pragma unroll
            for (int fn = 0; fn < 8; ++fn) {
                float x = acc[fm][fn][j];
                s += x; q += x * x;
            }
            rs[fm * 4 + j] = s; rq[fm * 4 + j] = q;
        }
#pragma unroll
    for (int m = 1; m < 16; m <<= 1)
#pragma unroll
        for (int i = 0; i < 16; ++i) {
            rs[i] += __shfl_xor(rs[i], m);
            rq[i] += __shfl_xor(rq[i], m);
        }
    if (ln15 == 0) {
#pragma unroll
        for (int fm = 0; fm < 4; ++fm)
#pragma unroll
            for (int j = 0; j < 4; ++j) {
                int row = fm * 16 + lg * 4 + j;
                lnred_s[row * 4 + wv] = rs[fm * 4 + j];
                lnred_q[row * 4 + wv] = rq[fm * 4 + j];
            }
    }
    __syncthreads();
    if (t < 64) {
        float s = lnred_s[t * 4] + lnred_s[t * 4 + 1] + lnred_s[t * 4 + 2] + lnred_s[t * 4 + 3];
        float q = lnred_q[t * 4] + lnred_q[t * 4 + 1] + lnred_q[t * 4 + 2] + lnred_q[t * 4 + 3];
        float mu = s * (1.0f / 512.0f);
        float var = q * (1.0f / 512.0f) - mu * mu;
        lnmv[t * 2] = mu;
        lnmv[t * 2 + 1] = rsqrtf(var + EPSV);
    }
    __syncthreads();

    // normalize + relu + packed row-major store (2 dwords = one full 128B line per thread)
#pragma unroll
    for (int fm = 0; fm < 4; ++fm)
#pragma unroll
        for (int j = 0; j < 4; ++j) {
            int rloc = fm * 16 + lg * 4 + j;
            long rglob = row0 + rloc;
            bool ok = rglob < NPTS;
            float mu = lnmv[rloc * 2], rstd = lnmv[rloc * 2 + 1];
#pragma unroll
            for (int fn = 0; fn < 8; ++fn) {
                float y = fmaxf((acc[fm][fn][j] - mu) * rstd * gv[fn] + bv[fn], 0.0f);
                acc[fm][fn][j] = ok ? y : 0.0f;
            }
            if (STORE) {
                unsigned ulo = pack4_fp8(acc[fm][0][j], acc[fm][1][j], acc[fm][2][j], acc[fm][3][j]);
                unsigned uhi = pack4_fp8(acc[fm][4][j], acc[fm][5][j], acc[fm][6][j], acc[fm][7][j]);
                char* base = (char*)Hout + rglob * DHID + wv * 128 + ln15 * 4;
                *(unsigned*)(base) = ulo;        // group wv*2   : fn 0..3
                *(unsigned*)(base + 64) = uhi;   // group wv*2+1 : fn 4..7
            }
        }

    // column partials over the block's 64 rows (sum or max); cols disjoint across waves
    float cp[8];
#pragma unroll
    for (int fn = 0; fn < 8; ++fn) {
        float p = 0.f;
#pragma unroll
        for (int fm = 0; fm < 4; ++fm)
#pragma unroll
            for (int j = 0; j < 4; ++j) {
                float v = acc[fm][fn][j];
                p = (REDOP == 0) ? (p + v) : fmaxf(p, v);
            }
        cp[fn] = p;
    }
#pragma unroll
    for (int m = 16; m < 64; m <<= 1)
#pragma unroll
        for (int fn = 0; fn < 8; ++fn) {
            float o = __shfl_xor(cp[fn], m);
            cp[fn] = (REDOP == 0) ? (cp[fn] + o) : fmaxf(cp[fn], o);
        }
    if (lane < 16) {
#pragma unroll
        for (int fn = 0; fn < 8; ++fn)
            red_out[(long)blockIdx.x * 512 + wv * 128 + fn * 16 + lane] = cp[fn];
    }
}

extern "C" void kernel_launch(void* const* d_in, const int* in_sizes, int n_in,
                              void* d_out, int out_size, void* d_ws, size_t ws_size,
                              hipStream_t stream) {
    const float* in_set = (const float*)d_in[0];
    const float* A0 = (const float*)d_in[1];
    const float* B0 = (const float*)d_in[2];
    const float* A1 = (const float*)d_in[3];
    const float* B1 = (const float*)d_in[4];
    const float* A2 = (const float*)d_in[5];
    const float* B2 = (const float*)d_in[6];
    const float* ga = (const float*)d_in[7];
    const float* be = (const float*)d_in[8];
    const float* ow = (const float*)d_in[9];
    const float* ob = (const float*)d_in[10];
    float* outp = (float*)d_out;
    char* ws = (char*)d_ws;

    unsigned char* in_f8 = (unsigned char*)(ws + OFF_INBF);
    unsigned long long* W0p = (unsigned long long*)(ws + OFF_W0);
    unsigned long long* W1p = (unsigned long long*)(ws + OFF_W1);
    unsigned long long* W2p = (unsigned long long*)(ws + OFF_W2);
    float* c0 = (float*)(ws + OFF_C0);
    float* c1 = (float*)(ws + OFF_C1);
    float* c2 = (float*)(ws + OFF_C2);
    float* parts = (float*)(ws + OFF_PARTS);
    float* parts2 = (float*)(ws + OFF_PARTS2);
    float* parts3 = (float*)(ws + OFF_PARTS3);
    unsigned char* h1 = (unsigned char*)(ws + OFF_H1);
    unsigned char* h2 = (unsigned char*)(ws + OFF_H2);

    const int nblk = (NPTS + 63) / 64;  // 1563

    cvt_pack_kernel<<<1024, 256, 0, stream>>>(in_set, in_f8);
    wpack_all_kernel<<<288, 256, 0, stream>>>(A0, B0, A1, B1, A2, B2, W0p, W1p, W2p);

    // c0 = colsum(in_set) @ B0^T  (all fp32 — the numerically critical path), wide+shallow
    colsum_in_kernel<<<512, 256, 0, stream>>>(in_set, parts);                       // [512][128]
    part_reduceW_kernel<<<64, 128, 0, stream>>>(parts, 512, 128, 0, parts2);        // [64][128]
    part_reduceW_kernel<<<8, 128, 0, stream>>>(parts2, 64, 128, 0, parts3);         // [8][128]
    gemv_fold_kernel<<<512, 64, 0, stream>>>(parts3, 128, B0, nullptr, 0, c0);

    layer_kernel<128, true, 0><<<nblk, 256, 0, stream>>>(in_f8, W0p, c0, ga, be, h1, parts);
    part_reduceW_kernel<<<64, 512, 0, stream>>>(parts, nblk, 512, 0, parts2);
    part_reduceW_kernel<<<8, 512, 0, stream>>>(parts2, 64, 512, 0, parts3);
    gemv_fold_kernel<<<512, 64, 0, stream>>>(parts3, 512, B1, nullptr, 0, c1);

    layer_kernel<512, true, 0><<<nblk, 256, 0, stream>>>(h1, W1p, c1, ga, be, h2, parts);
    part_reduceW_kernel<<<64, 512, 0, stream>>>(parts, nblk, 512, 0, parts2);
    part_reduceW_kernel<<<8, 512, 0, stream>>>(parts2, 64, 512, 0, parts3);
    gemv_fold_kernel<<<512, 64, 0, stream>>>(parts3, 512, B2, nullptr, 0, c2);

    // layer 2: no h3 store; fused column-max partials; final = (max-fold) @ ow^T + ob
    layer_kernel<512, false, 1><<<nblk, 256, 0, stream>>>(h2, W2p, c2, ga, be, nullptr, parts);
    part_reduceW_kernel<<<64, 512, 0, stream>>>(parts, nblk, 512, 1, parts2);
    part_reduceW_kernel<<<8, 512, 0, stream>>>(parts2, 64, 512, 1, parts3);
    gemv_fold_kernel<<<256, 64, 0, stream>>>(parts3, 512, ow, ob, 1, outp);
}